// Round 1
// baseline (4061.209 us; speedup 1.0000x reference)
//
#include <hip/hip_runtime.h>
#include <stdint.h>
#include <math.h>

// Replicate jax.random threefry2x32 exactly (jax_threefry_partitionable=True).
#define PARTITIONABLE 1

namespace {

constexpr int kB = 4096;
constexpr int kN = 256;
constexpr int kSweeps = 200;
constexpr int kSamp = 8;                 // samples per block
constexpr int kBlocks = kB / kSamp;      // 512
constexpr int kBN = kB * kN;             // 1048576 sites

struct K2 { uint32_t a, b; };

__host__ __device__ constexpr uint32_t crotl(uint32_t x, int d) {
  return (x << d) | (x >> (32 - d));
}

// Threefry-2x32, 20 rounds, exactly as jax/_src/prng.py
__host__ __device__ constexpr K2 ctf(uint32_t k0, uint32_t k1, uint32_t c0, uint32_t c1) {
  uint32_t ks0 = k0, ks1 = k1, ks2 = k0 ^ k1 ^ 0x1BD11BDAu;
  uint32_t x0 = c0 + ks0, x1 = c1 + ks1;
  const int r0[4] = {13, 15, 26, 6};
  const int r1[4] = {17, 29, 16, 24};
  for (int i = 0; i < 4; ++i) { x0 += x1; x1 = crotl(x1, r0[i]); x1 ^= x0; }
  x0 += ks1; x1 += ks2 + 1u;
  for (int i = 0; i < 4; ++i) { x0 += x1; x1 = crotl(x1, r1[i]); x1 ^= x0; }
  x0 += ks2; x1 += ks0 + 2u;
  for (int i = 0; i < 4; ++i) { x0 += x1; x1 = crotl(x1, r0[i]); x1 ^= x0; }
  x0 += ks0; x1 += ks1 + 3u;
  for (int i = 0; i < 4; ++i) { x0 += x1; x1 = crotl(x1, r1[i]); x1 ^= x0; }
  x0 += ks1; x1 += ks2 + 4u;
  for (int i = 0; i < 4; ++i) { x0 += x1; x1 = crotl(x1, r0[i]); x1 ^= x0; }
  x0 += ks2; x1 += ks0 + 5u;
  return K2{x0, x1};
}

struct KeyTable {
  uint32_t s0k[2];               // key for initial spins (k0)
  uint32_t sk[kSweeps][4];       // per sweep: k1a,k1b (accept), k2a,k2b (mask)
};

constexpr KeyTable make_keys() {
  KeyTable t{};
  K2 root{0u, 42u};              // jax.random.key(42) -> (hi=0, lo=42)
#if PARTITIONABLE
  K2 k0 = ctf(root.a, root.b, 0u, 0u);
  K2 kl = ctf(root.a, root.b, 0u, 1u);
#else
  K2 p0 = ctf(root.a, root.b, 0u, 2u);
  K2 p1 = ctf(root.a, root.b, 1u, 3u);
  K2 k0{p0.a, p1.a};
  K2 kl{p0.b, p1.b};
#endif
  t.s0k[0] = k0.a; t.s0k[1] = k0.b;
  K2 k = kl;
  for (int s = 0; s < kSweeps; ++s) {
#if PARTITIONABLE
    K2 kn = ctf(k.a, k.b, 0u, 0u);
    K2 k1 = ctf(k.a, k.b, 0u, 1u);
    K2 k2 = ctf(k.a, k.b, 0u, 2u);
#else
    K2 q0 = ctf(k.a, k.b, 0u, 3u);
    K2 q1 = ctf(k.a, k.b, 1u, 4u);
    K2 q2 = ctf(k.a, k.b, 2u, 5u);
    K2 kn{q0.a, q1.a};
    K2 k1{q2.a, q0.b};
    K2 k2{q1.b, q2.b};
#endif
    t.sk[s][0] = k1.a; t.sk[s][1] = k1.b;
    t.sk[s][2] = k2.a; t.sk[s][3] = k2.b;
    k = kn;
  }
  return t;
}

__constant__ KeyTable g_keys = make_keys();

__device__ __forceinline__ uint32_t rng_bits32(uint32_t ka, uint32_t kb, uint32_t m) {
#if PARTITIONABLE
  K2 r = ctf(ka, kb, 0u, m);
  return r.a ^ r.b;
#else
  constexpr uint32_t H = (uint32_t)(kB * kN / 2);
  uint32_t p = (m < H) ? m : (m - H);
  K2 r = ctf(ka, kb, p, p + H);
  return (m < H) ? r.a : r.b;
#endif
}

__device__ __forceinline__ float bits_to_uniform(uint32_t bits) {
  // jax: bitcast(bits >> 9 | 0x3f800000) - 1.0
  return __uint_as_float((bits >> 9) | 0x3f800000u) - 1.0f;
}

__global__ void prep_kernel(const float* __restrict__ gamma,
                            float* __restrict__ jsym,
                            float* __restrict__ betas) {
  int e = blockIdx.x * blockDim.x + threadIdx.x;   // 0..65535
  int i = e / kN, j = e % kN;
  float v = 0.0f;
  if (i < j) v = gamma[i * kN + j];
  else if (i > j) v = gamma[j * kN + i];
  jsym[e] = v;
  if (e < kSweeps) {
    double l0 = log(0.1), l1 = log(5.0);
    betas[e] = (float)exp(l0 + (l1 - l0) * (double)e / (double)(kSweeps - 1));
  }
}

// Precompute accept/mask randoms: one packed word per (sweep, site).
//   w = (bits1 >> 9) << 1 | (bits2 >> 31)
// u1 = bitcast((w>>1)|0x3f800000)-1  (bit-identical to bits_to_uniform(bits1))
// mask passes  <=>  u2 < 0.5  <=>  bit31(bits2)==0  <=>  (w & 1) == 0
__global__ __launch_bounds__(256) void rng_gen_kernel(uint32_t* __restrict__ out,
                                                      int t0) {
  const int t = t0 + blockIdx.y;
  const uint32_t k1a = g_keys.sk[t][0], k1b = g_keys.sk[t][1];
  const uint32_t k2a = g_keys.sk[t][2], k2b = g_keys.sk[t][3];
  const uint32_t m0 = (uint32_t)(blockIdx.x * blockDim.x + threadIdx.x) * 4u;
  uint32_t w[4];
#pragma unroll
  for (int u = 0; u < 4; ++u) {
    uint32_t m = m0 + (uint32_t)u;
    uint32_t b1 = rng_bits32(k1a, k1b, m);
    uint32_t b2 = rng_bits32(k2a, k2b, m);
    w[u] = ((b1 >> 9) << 1) | (b2 >> 31);
  }
  uint4 v; v.x = w[0]; v.y = w[1]; v.z = w[2]; v.w = w[3];
  *(uint4*)(out + (size_t)blockIdx.y * (size_t)kBN + m0) = v;
}

// PRE=true: randoms streamed from precomputed buffer (rng != nullptr)
// PRE=false: full in-kernel threefry fallback (small-workspace path)
template <bool PRE>
__global__ __launch_bounds__(256) void anneal_kernel(
    const float* __restrict__ thetas, const float* __restrict__ jsym,
    const float* __restrict__ betas, const uint32_t* __restrict__ rng,
    float* __restrict__ s_state, float* __restrict__ out, int t0, int nt) {
  // double-buffered spins: one barrier per sweep instead of two
  __shared__ __align__(16) float sh_s[2][kSamp][kN];
  __shared__ float sh_red[kSamp][4];

  const int i = threadIdx.x;           // spin index
  const int b0 = blockIdx.x * kSamp;   // first sample of this block

  float th[kSamp], sreg[kSamp];
#pragma unroll
  for (int g = 0; g < kSamp; ++g) th[g] = thetas[(b0 + g) * kN + i];

  if (t0 == 0) {
    // s0 = where(bernoulli(k0, 0.5), 1, -1) ; bernoulli = uniform < 0.5
#pragma unroll
    for (int g = 0; g < kSamp; ++g) {
      uint32_t m = (uint32_t)((b0 + g) * kN + i);
      float u = bits_to_uniform(rng_bits32(g_keys.s0k[0], g_keys.s0k[1], m));
      sreg[g] = (u < 0.5f) ? 1.0f : -1.0f;
    }
  } else {
#pragma unroll
    for (int g = 0; g < kSamp; ++g) sreg[g] = s_state[(b0 + g) * kN + i];
  }
#pragma unroll
  for (int g = 0; g < kSamp; ++g) sh_s[0][g][i] = sreg[g];
  __syncthreads();

  // row i of Jsym; by symmetry local_i = sum_j Jsym[i][j] * s[j]
  const float4* __restrict__ jrow = (const float4*)(jsym + i * kN);
  int cur = 0;

  for (int tt = 0; tt < nt; ++tt) {
    const int t = t0 + tt;
    const float beta = betas[t];

    uint32_t w[kSamp];
    if (PRE) {
      // issue early; consumed only after the matvec -> latency fully hidden
      const uint32_t* __restrict__ rp = rng + (size_t)tt * (size_t)kBN + i;
#pragma unroll
      for (int g = 0; g < kSamp; ++g) w[g] = rp[(b0 + g) * kN];
    }

    float acc[kSamp];
#pragma unroll
    for (int g = 0; g < kSamp; ++g) acc[g] = 0.0f;

    const float (*sc)[kN] = sh_s[cur];
    // software-pipelined jrow loads: 4 float4 (64B) prefetched one group ahead,
    // ~256 FMA-cycles of cover for the ~200cy L2 latency.
    float4 p0 = jrow[0], p1 = jrow[1], p2 = jrow[2], p3 = jrow[3];
    for (int q = 0; q < kN / 16; ++q) {          // 16 iterations
      float4 c0 = p0, c1 = p1, c2 = p2, c3 = p3;
      if (q < kN / 16 - 1) {
        p0 = jrow[q * 4 + 4]; p1 = jrow[q * 4 + 5];
        p2 = jrow[q * 4 + 6]; p3 = jrow[q * 4 + 7];
      }
#pragma unroll
      for (int g = 0; g < kSamp; ++g) {
        const float* sp = &sc[g][q * 16];
        float4 s0 = *(const float4*)(sp);
        float4 s1 = *(const float4*)(sp + 4);
        float4 s2 = *(const float4*)(sp + 8);
        float4 s3 = *(const float4*)(sp + 12);
        float a = acc[g];
        // strictly ascending j: exact same summation order as reference
        a = fmaf(c0.x, s0.x, a); a = fmaf(c0.y, s0.y, a);
        a = fmaf(c0.z, s0.z, a); a = fmaf(c0.w, s0.w, a);
        a = fmaf(c1.x, s1.x, a); a = fmaf(c1.y, s1.y, a);
        a = fmaf(c1.z, s1.z, a); a = fmaf(c1.w, s1.w, a);
        a = fmaf(c2.x, s2.x, a); a = fmaf(c2.y, s2.y, a);
        a = fmaf(c2.z, s2.z, a); a = fmaf(c2.w, s2.w, a);
        a = fmaf(c3.x, s3.x, a); a = fmaf(c3.y, s3.y, a);
        a = fmaf(c3.z, s3.z, a); a = fmaf(c3.w, s3.w, a);
        acc[g] = a;
      }
    }

    const int nxt = cur ^ 1;
    if (PRE) {
#pragma unroll
      for (int g = 0; g < kSamp; ++g) {
        float s = sreg[g];
        float local = th[g] + acc[g];
        float dE = -2.0f * s * local;          // exact: (-2*s) is a power of two
        float p = expf(-beta * dE);
        float u1 = __uint_as_float((w[g] >> 1) | 0x3f800000u) - 1.0f;
        if ((u1 < p) && ((w[g] & 1u) == 0u)) s = -s;   // accept & mask
        sreg[g] = s;
        sh_s[nxt][g][i] = s;                   // always write next buffer
      }
    } else {
      const uint32_t k1a = g_keys.sk[t][0], k1b = g_keys.sk[t][1];
      const uint32_t k2a = g_keys.sk[t][2], k2b = g_keys.sk[t][3];
#pragma unroll
      for (int g = 0; g < kSamp; ++g) {
        float s = sreg[g];
        float local = th[g] + acc[g];
        float dE = -2.0f * s * local;
        float p = expf(-beta * dE);
        uint32_t m = (uint32_t)((b0 + g) * kN + i);
        uint32_t b1 = rng_bits32(k1a, k1b, m);
        uint32_t b2 = rng_bits32(k2a, k2b, m);
        float u1 = bits_to_uniform(b1);
        if ((u1 < p) && ((b2 >> 31) == 0u)) s = -s;  // u2<0.5 <=> bit31==0
        sreg[g] = s;
        sh_s[nxt][g][i] = s;
      }
    }
    __syncthreads();   // writes visible before next sweep reads
    cur = nxt;
  }

  if (t0 + nt < kSweeps) {
    // chunked run: hand spins (exact +-1.0f) to the next chunk
#pragma unroll
    for (int g = 0; g < kSamp; ++g) s_state[(b0 + g) * kN + i] = sreg[g];
    return;
  }

  // E_b = sum_i s_i*theta_i + 0.5 * sum_i s_i * (Jsym s)_i
  float acc[kSamp];
#pragma unroll
  for (int g = 0; g < kSamp; ++g) acc[g] = 0.0f;
  const float (*sf)[kN] = sh_s[cur];
  for (int jj = 0; jj < kN / 4; ++jj) {
    float4 jv = jrow[jj];
#pragma unroll
    for (int g = 0; g < kSamp; ++g) {
      float4 sv = *(const float4*)&sf[g][jj * 4];
      acc[g] = fmaf(jv.x, sv.x, acc[g]);
      acc[g] = fmaf(jv.y, sv.y, acc[g]);
      acc[g] = fmaf(jv.z, sv.z, acc[g]);
      acc[g] = fmaf(jv.w, sv.w, acc[g]);
    }
  }

  const int lane = threadIdx.x & 63;
  const int wid = threadIdx.x >> 6;
#pragma unroll
  for (int g = 0; g < kSamp; ++g) {
    float v = sreg[g] * th[g] + 0.5f * (sreg[g] * acc[g]);
#pragma unroll
    for (int off = 32; off > 0; off >>= 1) v += __shfl_down(v, off);
    if (lane == 0) sh_red[g][wid] = v;
  }
  __syncthreads();
  if (threadIdx.x < kSamp) {
    int g = threadIdx.x;
    out[b0 + g] = sh_red[g][0] + sh_red[g][1] + sh_red[g][2] + sh_red[g][3];
  }
}

}  // namespace

extern "C" void kernel_launch(void* const* d_in, const int* in_sizes, int n_in,
                              void* d_out, int out_size, void* d_ws, size_t ws_size,
                              hipStream_t stream) {
  const float* thetas = (const float*)d_in[0];   // [4096, 256]
  const float* gamma  = (const float*)d_in[1];   // [256, 256]
  char* ws = (char*)d_ws;

  // workspace layout
  constexpr size_t kJsymOff  = 0;                          // 256 KiB
  constexpr size_t kBetaOff  = (size_t)kN * kN * 4;        // 262144, 800 B used
  constexpr size_t kStateOff = kBetaOff + 4096;            // 266240, 4 MiB
  constexpr size_t kSlab     = (size_t)kBN * 4;            // 4 MiB per sweep
  constexpr size_t kRngOff   = kStateOff + kSlab;          // 4460544

  float* jsym    = (float*)(ws + kJsymOff);
  float* betas   = (float*)(ws + kBetaOff);
  float* s_state = (float*)(ws + kStateOff);
  uint32_t* rngbuf = (uint32_t*)(ws + kRngOff);

  hipLaunchKernelGGL(prep_kernel, dim3(kN), dim3(kN), 0, stream, gamma, jsym, betas);

  int chunk = 0;
  if (ws_size > kRngOff) {
    size_t avail = (ws_size - kRngOff) / kSlab;      // whole sweeps that fit
    chunk = avail > (size_t)kSweeps ? kSweeps : (int)avail;
  }

  if (chunk >= 1) {
    int done = 0;
    while (done < kSweeps) {
      int c = (kSweeps - done) < chunk ? (kSweeps - done) : chunk;
      hipLaunchKernelGGL(rng_gen_kernel, dim3(kBN / 1024, c), dim3(256), 0, stream,
                         rngbuf, done);
      hipLaunchKernelGGL((anneal_kernel<true>), dim3(kBlocks), dim3(256), 0, stream,
                         thetas, jsym, betas, rngbuf, s_state, (float*)d_out,
                         done, c);
      done += c;
    }
  } else {
    // workspace too small for even one sweep slab: in-kernel RNG fallback
    hipLaunchKernelGGL((anneal_kernel<false>), dim3(kBlocks), dim3(256), 0, stream,
                       thetas, jsym, betas, (const uint32_t*)nullptr, s_state,
                       (float*)d_out, 0, kSweeps);
  }
}